// Round 1
// baseline (2724.651 us; speedup 1.0000x reference)
//
#include <hip/hip_runtime.h>
#include <math.h>

#define NR 4096
#define DD 512
#define MM 50000
#define CAP 1024
#define T0 0.10f

typedef unsigned int u32;

// ---------------- ws layout ----------------
// [0,       16384)  : cnt  (4096 u32)          -- zeroed each launch
// [16384,   20480)  : geom partials (1024 f32) -- fully overwritten
// [20480,   20484)  : e_geom scalar
// [32768,   32768 + 4096*1024*8) : cand (uint2 = {float bits, col})

// ============ big GEMM x @ mu^T with threshold push ============
__global__ __launch_bounds__(256) void k_gemm_topk(
    const float* __restrict__ x, const float* __restrict__ mu,
    u32* __restrict__ cnt, uint2* __restrict__ cand)
{
    __shared__ float As[16][128];
    __shared__ float Bs[16][128];
    const int t  = threadIdx.x;
    const int r0 = blockIdx.y * 128;
    const int c0 = blockIdx.x * 128;
    const int lr = t >> 1;          // 0..127 (row within tile for loading)
    const int lk = (t & 1) * 8;     // 0 or 8
    const int ty = t >> 4;          // 0..15
    const int tx = t & 15;          // 0..15

    float acc[8][8];
#pragma unroll
    for (int i = 0; i < 8; ++i)
#pragma unroll
        for (int j = 0; j < 8; ++j) acc[i][j] = 0.f;

    for (int kk = 0; kk < DD; kk += 16) {
        float4 a0 = *reinterpret_cast<const float4*>(&x[(size_t)(r0 + lr) * DD + kk + lk]);
        float4 a1 = *reinterpret_cast<const float4*>(&x[(size_t)(r0 + lr) * DD + kk + lk + 4]);
        float4 b0 = make_float4(0.f, 0.f, 0.f, 0.f);
        float4 b1 = make_float4(0.f, 0.f, 0.f, 0.f);
        const int c = c0 + lr;
        if (c < MM) {
            b0 = *reinterpret_cast<const float4*>(&mu[(size_t)c * DD + kk + lk]);
            b1 = *reinterpret_cast<const float4*>(&mu[(size_t)c * DD + kk + lk + 4]);
        }
        __syncthreads();
        As[lk + 0][lr] = a0.x; As[lk + 1][lr] = a0.y; As[lk + 2][lr] = a0.z; As[lk + 3][lr] = a0.w;
        As[lk + 4][lr] = a1.x; As[lk + 5][lr] = a1.y; As[lk + 6][lr] = a1.z; As[lk + 7][lr] = a1.w;
        Bs[lk + 0][lr] = b0.x; Bs[lk + 1][lr] = b0.y; Bs[lk + 2][lr] = b0.z; Bs[lk + 3][lr] = b0.w;
        Bs[lk + 4][lr] = b1.x; Bs[lk + 5][lr] = b1.y; Bs[lk + 6][lr] = b1.z; Bs[lk + 7][lr] = b1.w;
        __syncthreads();
#pragma unroll
        for (int k = 0; k < 16; ++k) {
            float a[8], b[8];
            *reinterpret_cast<float4*>(&a[0]) = *reinterpret_cast<const float4*>(&As[k][ty * 8]);
            *reinterpret_cast<float4*>(&a[4]) = *reinterpret_cast<const float4*>(&As[k][ty * 8 + 4]);
            *reinterpret_cast<float4*>(&b[0]) = *reinterpret_cast<const float4*>(&Bs[k][tx * 8]);
            *reinterpret_cast<float4*>(&b[4]) = *reinterpret_cast<const float4*>(&Bs[k][tx * 8 + 4]);
#pragma unroll
            for (int i = 0; i < 8; ++i)
#pragma unroll
                for (int j = 0; j < 8; ++j)
                    acc[i][j] = fmaf(a[i], b[j], acc[i][j]);
        }
    }

#pragma unroll
    for (int i = 0; i < 8; ++i) {
        const int row = r0 + ty * 8 + i;
#pragma unroll
        for (int j = 0; j < 8; ++j) {
            const int col = c0 + tx * 8 + j;
            const float v = acc[i][j];
            if (v >= T0 && col < MM) {
                u32 pos = atomicAdd(&cnt[row], 1u);
                if (pos < CAP)
                    cand[(size_t)row * CAP + pos] = make_uint2(__float_as_uint(v), (u32)col);
            }
        }
    }
}

// ============ S = x @ x^T geometric-energy partial sums ============
__global__ __launch_bounds__(256) void k_gemm_geom(
    const float* __restrict__ x, float* __restrict__ partial)
{
    __shared__ float As[16][128];
    __shared__ float Bs[16][128];
    __shared__ float red[4];
    const int t  = threadIdx.x;
    const int r0 = blockIdx.y * 128;
    const int c0 = blockIdx.x * 128;
    const int lr = t >> 1;
    const int lk = (t & 1) * 8;
    const int ty = t >> 4;
    const int tx = t & 15;

    float acc[8][8];
#pragma unroll
    for (int i = 0; i < 8; ++i)
#pragma unroll
        for (int j = 0; j < 8; ++j) acc[i][j] = 0.f;

    for (int kk = 0; kk < DD; kk += 16) {
        float4 a0 = *reinterpret_cast<const float4*>(&x[(size_t)(r0 + lr) * DD + kk + lk]);
        float4 a1 = *reinterpret_cast<const float4*>(&x[(size_t)(r0 + lr) * DD + kk + lk + 4]);
        float4 b0 = *reinterpret_cast<const float4*>(&x[(size_t)(c0 + lr) * DD + kk + lk]);
        float4 b1 = *reinterpret_cast<const float4*>(&x[(size_t)(c0 + lr) * DD + kk + lk + 4]);
        __syncthreads();
        As[lk + 0][lr] = a0.x; As[lk + 1][lr] = a0.y; As[lk + 2][lr] = a0.z; As[lk + 3][lr] = a0.w;
        As[lk + 4][lr] = a1.x; As[lk + 5][lr] = a1.y; As[lk + 6][lr] = a1.z; As[lk + 7][lr] = a1.w;
        Bs[lk + 0][lr] = b0.x; Bs[lk + 1][lr] = b0.y; Bs[lk + 2][lr] = b0.z; Bs[lk + 3][lr] = b0.w;
        Bs[lk + 4][lr] = b1.x; Bs[lk + 5][lr] = b1.y; Bs[lk + 6][lr] = b1.z; Bs[lk + 7][lr] = b1.w;
        __syncthreads();
#pragma unroll
        for (int k = 0; k < 16; ++k) {
            float a[8], b[8];
            *reinterpret_cast<float4*>(&a[0]) = *reinterpret_cast<const float4*>(&As[k][ty * 8]);
            *reinterpret_cast<float4*>(&a[4]) = *reinterpret_cast<const float4*>(&As[k][ty * 8 + 4]);
            *reinterpret_cast<float4*>(&b[0]) = *reinterpret_cast<const float4*>(&Bs[k][tx * 8]);
            *reinterpret_cast<float4*>(&b[4]) = *reinterpret_cast<const float4*>(&Bs[k][tx * 8 + 4]);
#pragma unroll
            for (int i = 0; i < 8; ++i)
#pragma unroll
                for (int j = 0; j < 8; ++j)
                    acc[i][j] = fmaf(a[i], b[j], acc[i][j]);
        }
    }

    float local = 0.f;
#pragma unroll
    for (int i = 0; i < 8; ++i) {
        const int row = r0 + ty * 8 + i;
#pragma unroll
        for (int j = 0; j < 8; ++j) {
            const int col = c0 + tx * 8 + j;
            if (row != col) {
                float s = fminf(acc[i][j], 0.9999f);
                local += -logf(1.0f - s + 1e-4f);
            }
        }
    }
    // block reduce (fixed tree -> deterministic)
#pragma unroll
    for (int off = 32; off >= 1; off >>= 1)
        local += __shfl_xor(local, off, 64);
    const int wave = t >> 6, lane = t & 63;
    if (lane == 0) red[wave] = local;
    __syncthreads();
    if (t == 0) {
        float s = red[0] + red[1] + red[2] + red[3];
        partial[blockIdx.y * 32 + blockIdx.x] = s;
    }
}

__global__ void k_reduce_geom(const float* __restrict__ partial, float* __restrict__ egeom)
{
    __shared__ float red[16];
    const int t = threadIdx.x;
    float v = partial[t];
#pragma unroll
    for (int off = 32; off >= 1; off >>= 1)
        v += __shfl_xor(v, off, 64);
    const int wave = t >> 6, lane = t & 63;
    if (lane == 0) red[wave] = v;
    __syncthreads();
    if (t == 0) {
        float s = 0.f;
        for (int i = 0; i < 16; ++i) s += red[i];
        egeom[0] = s / ((float)NR * (float)(NR - 1));
    }
}

// ============ per-row top-32 selection + epilogue ============
__global__ __launch_bounds__(256) void k_finalize(
    const uint2* __restrict__ cand, const u32* __restrict__ cnt,
    const float* __restrict__ alpha, const float* __restrict__ kappa,
    const float* __restrict__ Ww, const float* __restrict__ Wb,
    const float* __restrict__ egeom, float* __restrict__ out)
{
    __shared__ float vals[4][CAP];
    __shared__ int   idxs[4][CAP];
    __shared__ float selv[4][32];
    __shared__ int   seli[4][32];

    const int t = threadIdx.x;
    const int wave = t >> 6, lane = t & 63;
    const int row = blockIdx.x * 4 + wave;
    const int c = (int)min(cnt[row], (u32)CAP);

    for (int s = lane; s < c; s += 64) {
        uint2 e = cand[(size_t)row * CAP + s];
        vals[wave][s] = __uint_as_float(e.x);
        idxs[wave][s] = (int)e.y;
    }
    __syncthreads();

    // 32 argmax iterations -> selv sorted descending
    for (int k = 0; k < 32; ++k) {
        float best = -INFINITY; int bpos = -1;
        for (int s = lane; s < c; s += 64) {
            float v = vals[wave][s];
            if (v > best) { best = v; bpos = s; }
        }
#pragma unroll
        for (int off = 32; off >= 1; off >>= 1) {
            float v2 = __shfl_xor(best, off, 64);
            int   p2 = __shfl_xor(bpos, off, 64);
            if (v2 > best) { best = v2; bpos = p2; }
        }
        if (lane == 0) {
            selv[wave][k] = best;
            seli[wave][k] = (bpos >= 0) ? idxs[wave][bpos] : 0;
            if (bpos >= 0) vals[wave][bpos] = -INFINITY;
        }
        __syncthreads();
    }

    // epilogue math on lanes 0..31
    float v = -INFINITY; int id = 0;
    if (lane < 32) { v = selv[wave][lane]; id = seli[wave][lane]; }
    const bool valid = (lane < 32) && (v > -1e30f);
    const float a  = alpha[id];
    const float kp = kappa[id];
    float imp = valid ? fmaxf(kp, 1e-4f) : 0.f;
    float expo = a * (v - 1.0f) * 10.0f;   // alpha*(dots-1)/TEMP

    float simp = imp;
#pragma unroll
    for (int off = 16; off >= 1; off >>= 1) simp += __shfl_xor(simp, off, 32);

    float w  = fmaxf(imp / simp, 1e-8f);
    float tk = valid ? (expo + logf(w)) : -INFINITY;
    float mx = tk;
#pragma unroll
    for (int off = 16; off >= 1; off >>= 1) mx = fmaxf(mx, __shfl_xor(mx, off, 32));
    float se = valid ? expf(tk - mx) : 0.f;
#pragma unroll
    for (int off = 16; off >= 1; off >>= 1) se += __shfl_xor(se, off, 32);

    if (lane == 0) {
        float esplat = -(mx + logf(se));
        float u  = selv[wave][0];
        float vv = selv[wave][1];
        float z = Ww[0] * u + Ww[1] * vv + Ww[2] * u * vv + Wb[0];
        float ecomp = 1.f / (1.f + expf(-z));
        out[row] = esplat + 0.1f * egeom[0] + 0.1f * ecomp;
    }
}

extern "C" void kernel_launch(void* const* d_in, const int* in_sizes, int n_in,
                              void* d_out, int out_size, void* d_ws, size_t ws_size,
                              hipStream_t stream)
{
    const float* x     = (const float*)d_in[0];
    const float* mu    = (const float*)d_in[1];
    const float* alpha = (const float*)d_in[2];
    const float* kappa = (const float*)d_in[3];
    const float* Ww    = (const float*)d_in[4];
    const float* Wb    = (const float*)d_in[5];
    float* out = (float*)d_out;

    char* ws = (char*)d_ws;
    u32*   cnt     = (u32*)ws;
    float* partial = (float*)(ws + 16384);
    float* egeom   = (float*)(ws + 20480);
    uint2* cand    = (uint2*)(ws + 32768);

    hipMemsetAsync(cnt, 0, NR * sizeof(u32), stream);

    dim3 g1((MM + 127) / 128, NR / 128);   // 391 x 32
    k_gemm_topk<<<g1, 256, 0, stream>>>(x, mu, cnt, cand);

    dim3 g2(NR / 128, NR / 128);           // 32 x 32
    k_gemm_geom<<<g2, 256, 0, stream>>>(x, partial);

    k_reduce_geom<<<1, 1024, 0, stream>>>(partial, egeom);

    k_finalize<<<NR / 4, 256, 0, stream>>>(cand, cnt, alpha, kappa, Ww, Wb, egeom, out);
}

// Round 2
// 1248.326 us; speedup vs baseline: 2.1826x; 2.1826x over previous
//
#include <hip/hip_runtime.h>
#include <math.h>

#define NR 4096
#define DD 512
#define MM 50000
#define CAP 640
#define TK 64
#define T0 0.105f

typedef unsigned int u32;
typedef unsigned short u16;
typedef short bf16x8 __attribute__((ext_vector_type(8)));
typedef float f32x4 __attribute__((ext_vector_type(4)));
typedef u16 u16x8 __attribute__((ext_vector_type(8)));

#define AS1 __attribute__((address_space(1)))
#define AS3 __attribute__((address_space(3)))

__device__ __forceinline__ u16 f2bf(float f) {
    u32 u = __float_as_uint(f);
    u32 r = (u + 0x7FFFu + ((u >> 16) & 1u)) >> 16;   // RNE
    return (u16)r;
}

// ---------------- ws layout ----------------
// [0,16384)            cnt (4096 u32)  -- zeroed each launch
// [16384,20480)        geom partials (1024 f32, fully written)
// [20480,20484)        e_geom scalar
// [32768, +4MB)        xb  (4096x512 bf16)
// [+4MB, +55.4MB)      mub (50000x512 bf16)
// [+55.4MB, +65.9MB)   cand keys (4096 x 640 u32 = {bf16val:16, idx:16})

__global__ __launch_bounds__(256) void k_cast(const float* __restrict__ src,
                                              u16* __restrict__ dst, int n8) {
    int i = blockIdx.x * 256 + threadIdx.x;
    if (i >= n8) return;
    const float4* s4 = (const float4*)src;
    float4 a = s4[(size_t)i * 2], b = s4[(size_t)i * 2 + 1];
    u16x8 o;
    o[0] = f2bf(a.x); o[1] = f2bf(a.y); o[2] = f2bf(a.z); o[3] = f2bf(a.w);
    o[4] = f2bf(b.x); o[5] = f2bf(b.y); o[6] = f2bf(b.z); o[7] = f2bf(b.w);
    *(u16x8*)(dst + (size_t)i * 8) = o;
}

// ============ bf16 MFMA GEMM x @ mu^T with threshold push ============
// 128x128 tile, BK=64, 4 waves (2x2, 64x64 each), global_load_lds w=16,
// LDS XOR-swizzle byte ^= ((row&7)<<4) applied via pre-swizzled SOURCE.
__global__ __launch_bounds__(256) void k_gemm_topk(
    const u16* __restrict__ xb, const u16* __restrict__ mub,
    u32* __restrict__ cnt, u32* __restrict__ cand)
{
    __shared__ uint4 smem[2048];          // 32 KB
    char* Asb = (char*)smem;              // 128x64 bf16 x-tile (swizzled)
    char* Bsb = (char*)(smem + 1024);     // 128x64 bf16 mu-tile

    const int t = threadIdx.x;
    const int lane = t & 63;
    const int wid = t >> 6;
    const int wr = wid >> 1, wc = wid & 1;
    const int fr = lane & 15, fq = lane >> 4;
    const int r0 = blockIdx.y * 128;
    const int c0 = blockIdx.x * 128;

    f32x4 acc[4][4];
    const f32x4 zero = {0.f, 0.f, 0.f, 0.f};
#pragma unroll
    for (int m = 0; m < 4; ++m)
#pragma unroll
        for (int n = 0; n < 4; ++n) acc[m][n] = zero;

    const int swz = (fr & 7) << 4;

    for (int kt = 0; kt < DD; kt += 64) {
        __syncthreads();
#pragma unroll
        for (int i = 0; i < 4; ++i) {
            const int L  = i * 4096 + t * 16;
            const int rw = L >> 7;
            const int cb = (L & 127) ^ ((rw & 7) << 4);
            const char* srcA = (const char*)xb + ((size_t)(r0 + rw) * DD + kt) * 2 + cb;
            __builtin_amdgcn_global_load_lds((const AS1 u32*)srcA, (AS3 u32*)(Asb + L), 16, 0, 0);
            int gr = c0 + rw; if (gr > MM - 1) gr = MM - 1;   // clamp, filtered at push
            const char* srcB = (const char*)mub + ((size_t)gr * DD + kt) * 2 + cb;
            __builtin_amdgcn_global_load_lds((const AS1 u32*)srcB, (AS3 u32*)(Bsb + L), 16, 0, 0);
        }
        __syncthreads();
#pragma unroll
        for (int kk = 0; kk < 64; kk += 32) {
            bf16x8 af[4], bfr[4];
#pragma unroll
            for (int m = 0; m < 4; ++m) {
                const int ra = wr * 64 + m * 16 + fr;
                af[m] = *(const bf16x8*)(Asb + ((ra << 7) | ((kk * 2 + fq * 16) ^ swz)));
            }
#pragma unroll
            for (int n = 0; n < 4; ++n) {
                const int rb = wc * 64 + n * 16 + fr;
                bfr[n] = *(const bf16x8*)(Bsb + ((rb << 7) | ((kk * 2 + fq * 16) ^ swz)));
            }
#pragma unroll
            for (int m = 0; m < 4; ++m)
#pragma unroll
                for (int n = 0; n < 4; ++n)
                    acc[m][n] = __builtin_amdgcn_mfma_f32_16x16x32_bf16(af[m], bfr[n], acc[m][n], 0, 0, 0);
        }
    }

    // C/D layout (m89): col = lane&15, row = (lane>>4)*4 + reg
#pragma unroll
    for (int m = 0; m < 4; ++m) {
        const int rowb = r0 + wr * 64 + m * 16 + fq * 4;
#pragma unroll
        for (int n = 0; n < 4; ++n) {
            const int col = c0 + wc * 64 + n * 16 + fr;
#pragma unroll
            for (int r = 0; r < 4; ++r) {
                const float v = acc[m][n][r];
                if (v >= T0 && col < MM) {
                    u32 pos = atomicAdd(&cnt[rowb + r], 1u);
                    if (pos < CAP)
                        cand[(size_t)(rowb + r) * CAP + pos] =
                            (((u32)f2bf(v)) << 16) | (u32)col;
                }
            }
        }
    }
}

// ============ x @ x^T geometric energy (bf16 MFMA, triangular) ============
__global__ __launch_bounds__(256) void k_geom(
    const u16* __restrict__ xb, float* __restrict__ partial)
{
    const int bx = blockIdx.x, by = blockIdx.y;
    const int t = threadIdx.x;
    if (bx < by) { if (t == 0) partial[by * 32 + bx] = 0.f; return; }

    __shared__ uint4 smem[2048];
    char* Asb = (char*)smem;
    char* Bsb = (char*)(smem + 1024);
    __shared__ float red[4];

    const int lane = t & 63;
    const int wid = t >> 6;
    const int wr = wid >> 1, wc = wid & 1;
    const int fr = lane & 15, fq = lane >> 4;
    const int r0 = by * 128;
    const int c0 = bx * 128;

    f32x4 acc[4][4];
    const f32x4 zero = {0.f, 0.f, 0.f, 0.f};
#pragma unroll
    for (int m = 0; m < 4; ++m)
#pragma unroll
        for (int n = 0; n < 4; ++n) acc[m][n] = zero;

    const int swz = (fr & 7) << 4;

    for (int kt = 0; kt < DD; kt += 64) {
        __syncthreads();
#pragma unroll
        for (int i = 0; i < 4; ++i) {
            const int L  = i * 4096 + t * 16;
            const int rw = L >> 7;
            const int cb = (L & 127) ^ ((rw & 7) << 4);
            const char* srcA = (const char*)xb + ((size_t)(r0 + rw) * DD + kt) * 2 + cb;
            __builtin_amdgcn_global_load_lds((const AS1 u32*)srcA, (AS3 u32*)(Asb + L), 16, 0, 0);
            const char* srcB = (const char*)xb + ((size_t)(c0 + rw) * DD + kt) * 2 + cb;
            __builtin_amdgcn_global_load_lds((const AS1 u32*)srcB, (AS3 u32*)(Bsb + L), 16, 0, 0);
        }
        __syncthreads();
#pragma unroll
        for (int kk = 0; kk < 64; kk += 32) {
            bf16x8 af[4], bfr[4];
#pragma unroll
            for (int m = 0; m < 4; ++m) {
                const int ra = wr * 64 + m * 16 + fr;
                af[m] = *(const bf16x8*)(Asb + ((ra << 7) | ((kk * 2 + fq * 16) ^ swz)));
            }
#pragma unroll
            for (int n = 0; n < 4; ++n) {
                const int rb = wc * 64 + n * 16 + fr;
                bfr[n] = *(const bf16x8*)(Bsb + ((rb << 7) | ((kk * 2 + fq * 16) ^ swz)));
            }
#pragma unroll
            for (int m = 0; m < 4; ++m)
#pragma unroll
                for (int n = 0; n < 4; ++n)
                    acc[m][n] = __builtin_amdgcn_mfma_f32_16x16x32_bf16(af[m], bfr[n], acc[m][n], 0, 0, 0);
        }
    }

    float local = 0.f;
#pragma unroll
    for (int m = 0; m < 4; ++m) {
        const int rowb = r0 + wr * 64 + m * 16 + fq * 4;
#pragma unroll
        for (int n = 0; n < 4; ++n) {
            const int col = c0 + wc * 64 + n * 16 + fr;
#pragma unroll
            for (int r = 0; r < 4; ++r) {
                if (rowb + r != col) {
                    float s = fminf(acc[m][n][r], 0.9999f);
                    local += -logf(1.0f - s + 1e-4f);
                }
            }
        }
    }
    if (bx > by) local *= 2.f;   // symmetric half counted twice

#pragma unroll
    for (int off = 32; off >= 1; off >>= 1) local += __shfl_xor(local, off, 64);
    if (lane == 0) red[wid] = local;
    __syncthreads();
    if (t == 0) partial[by * 32 + bx] = red[0] + red[1] + red[2] + red[3];
}

__global__ void k_reduce_geom(const float* __restrict__ partial, float* __restrict__ egeom)
{
    __shared__ float red[16];
    const int t = threadIdx.x;
    float v = partial[t];
#pragma unroll
    for (int off = 32; off >= 1; off >>= 1) v += __shfl_xor(v, off, 64);
    const int wave = t >> 6, lane = t & 63;
    if (lane == 0) red[wave] = v;
    __syncthreads();
    if (t == 0) {
        float s = 0.f;
        for (int i = 0; i < 16; ++i) s += red[i];
        egeom[0] = s / ((float)NR * (float)(NR - 1));
    }
}

// ============ top-64 by key -> exact fp32 recompute -> top-32 -> epilogue ====
__global__ __launch_bounds__(256) void k_finalize(
    const u32* __restrict__ cand, const u32* __restrict__ cnt,
    const float* __restrict__ x, const float* __restrict__ mu,
    const float* __restrict__ alpha, const float* __restrict__ kappa,
    const float* __restrict__ Ww, const float* __restrict__ Wb,
    const float* __restrict__ egeom, float* __restrict__ out)
{
    __shared__ u32   keys[4][CAP];
    __shared__ int   selid[4][TK];
    __shared__ float selex[4][TK];

    const int t = threadIdx.x, wave = t >> 6, lane = t & 63;
    const int row = blockIdx.x * 4 + wave;
    const int cn = (int)cnt[row];
    const int c = cn < CAP ? cn : CAP;

    for (int s = lane; s < c; s += 64)
        keys[wave][s] = cand[(size_t)row * CAP + s];
    __syncthreads();

    // iterative argmax: top-TK keys (value-major; distinct idx => no ties)
    for (int k = 0; k < TK; ++k) {
        u32 best = 0u; int bpos = -1;
        for (int s = lane; s < c; s += 64) {
            u32 v = keys[wave][s];
            if (v > best) { best = v; bpos = s; }
        }
#pragma unroll
        for (int off = 32; off >= 1; off >>= 1) {
            u32 v2 = __shfl_xor(best, off, 64);
            int p2 = __shfl_xor(bpos, off, 64);
            if (v2 > best) { best = v2; bpos = p2; }
        }
        if (lane == 0) {
            selid[wave][k] = (bpos >= 0) ? (int)(best & 0xFFFFu) : -1;
            if (bpos >= 0) keys[wave][bpos] = 0u;
        }
        __syncthreads();
    }

    // exact fp32 dots for the TK selected candidates
    float xr[8];
    {
        const float4* xp = (const float4*)(x + (size_t)row * DD);
        float4 a = xp[lane * 2], b = xp[lane * 2 + 1];
        xr[0] = a.x; xr[1] = a.y; xr[2] = a.z; xr[3] = a.w;
        xr[4] = b.x; xr[5] = b.y; xr[6] = b.z; xr[7] = b.w;
    }
    for (int s = 0; s < TK; ++s) {
        const int id = selid[wave][s];          // wave-uniform
        if (id >= 0) {
            const float4* mp = (const float4*)(mu + (size_t)id * DD);
            float4 a = mp[lane * 2], b = mp[lane * 2 + 1];
            float d = xr[0] * a.x + xr[1] * a.y + xr[2] * a.z + xr[3] * a.w
                    + xr[4] * b.x + xr[5] * b.y + xr[6] * b.z + xr[7] * b.w;
#pragma unroll
            for (int off = 32; off >= 1; off >>= 1) d += __shfl_xor(d, off, 64);
            if (lane == 0) selex[wave][s] = d;
        } else if (lane == 0) {
            selex[wave][s] = -INFINITY;
        }
    }
    __syncthreads();

    float v = selex[wave][lane];
    const int id = selid[wave][lane];
    bool alive = (id >= 0);

    // drop the 32 smallest exact values -> exact top-32 remains
    for (int rdrop = 0; rdrop < 32; ++rdrop) {
        float mn = alive ? v : INFINITY;
        int  mp2 = alive ? lane : 64;
#pragma unroll
        for (int off = 32; off >= 1; off >>= 1) {
            float m2 = __shfl_xor(mn, off, 64);
            int   p2 = __shfl_xor(mp2, off, 64);
            if (m2 < mn || (m2 == mn && p2 < mp2)) { mn = m2; mp2 = p2; }
        }
        if (lane == mp2) alive = false;
    }

    const float dv = alive ? v : -INFINITY;

    // top-1 / top-2 exact values (u, v of the reference)
    float m1 = dv; int p1 = alive ? lane : 64;
#pragma unroll
    for (int off = 32; off >= 1; off >>= 1) {
        float m2 = __shfl_xor(m1, off, 64);
        int   p2 = __shfl_xor(p1, off, 64);
        if (m2 > m1 || (m2 == m1 && p2 < p1)) { m1 = m2; p1 = p2; }
    }
    const float uu = m1;
    float s1 = (lane == p1) ? -INFINITY : dv;
#pragma unroll
    for (int off = 32; off >= 1; off >>= 1) s1 = fmaxf(s1, __shfl_xor(s1, off, 64));
    const float vv = s1;

    const int gid = alive ? id : 0;
    const float av = alpha[gid];
    const float kv = kappa[gid];
    float imp = alive ? fmaxf(kv, 1e-4f) : 0.f;
    float simp = imp;
#pragma unroll
    for (int off = 32; off >= 1; off >>= 1) simp += __shfl_xor(simp, off, 64);
    float w = fmaxf(imp / simp, 1e-8f);
    float tk = alive ? (av * (dv - 1.0f) * 10.0f + logf(w)) : -INFINITY;
    float mx = tk;
#pragma unroll
    for (int off = 32; off >= 1; off >>= 1) mx = fmaxf(mx, __shfl_xor(mx, off, 64));
    float se = alive ? expf(tk - mx) : 0.f;
#pragma unroll
    for (int off = 32; off >= 1; off >>= 1) se += __shfl_xor(se, off, 64);

    if (lane == 0) {
        float esplat = -(mx + logf(se));
        float z = Ww[0] * uu + Ww[1] * vv + Ww[2] * uu * vv + Wb[0];
        float ecomp = 1.f / (1.f + expf(-z));
        out[row] = esplat + 0.1f * egeom[0] + 0.1f * ecomp;
    }
}

extern "C" void kernel_launch(void* const* d_in, const int* in_sizes, int n_in,
                              void* d_out, int out_size, void* d_ws, size_t ws_size,
                              hipStream_t stream)
{
    const float* x     = (const float*)d_in[0];
    const float* mu    = (const float*)d_in[1];
    const float* alpha = (const float*)d_in[2];
    const float* kappa = (const float*)d_in[3];
    const float* Ww    = (const float*)d_in[4];
    const float* Wb    = (const float*)d_in[5];
    float* out = (float*)d_out;

    char* ws = (char*)d_ws;
    u32*   cnt     = (u32*)ws;
    float* partial = (float*)(ws + 16384);
    float* egeom   = (float*)(ws + 20480);
    u16*   xb      = (u16*)(ws + 32768);
    u16*   mub     = (u16*)(ws + 32768 + 4194304);
    u32*   cand    = (u32*)(ws + 32768 + 4194304 + 51200000);

    hipMemsetAsync(cnt, 0, NR * sizeof(u32), stream);

    k_cast<<<(NR * DD / 8) / 256, 256, 0, stream>>>(x, xb, NR * DD / 8);
    k_cast<<<(MM * DD / 8) / 256, 256, 0, stream>>>(mu, mub, MM * DD / 8);

    dim3 g1((MM + 127) / 128, NR / 128);   // 391 x 32
    k_gemm_topk<<<g1, 256, 0, stream>>>(xb, mub, cnt, cand);

    dim3 g2(32, 32);
    k_geom<<<g2, 256, 0, stream>>>(xb, partial);

    k_reduce_geom<<<1, 1024, 0, stream>>>(partial, egeom);

    k_finalize<<<NR / 4, 256, 0, stream>>>(cand, cnt, x, mu, alpha, kappa, Ww, Wb, egeom, out);
}

// Round 3
// 703.135 us; speedup vs baseline: 3.8750x; 1.7754x over previous
//
#include <hip/hip_runtime.h>
#include <math.h>

#define NR 4096
#define DD 512
#define MM 50000
#define CAP 640
#define TK 64
#define T0 0.105f

typedef unsigned int u32;
typedef unsigned short u16;
typedef short bf16x8 __attribute__((ext_vector_type(8)));
typedef float f32x4 __attribute__((ext_vector_type(4)));
typedef u16 u16x8 __attribute__((ext_vector_type(8)));

#define AS1 __attribute__((address_space(1)))
#define AS3 __attribute__((address_space(3)))

__device__ __forceinline__ u16 f2bf(float f) {
    u32 u = __float_as_uint(f);
    u32 r = (u + 0x7FFFu + ((u >> 16) & 1u)) >> 16;   // RNE
    return (u16)r;
}

// ---------------- ws layout ----------------
// [0,16384)            cnt (4096 u32)  -- zeroed each launch
// [16384,20480)        geom partials (1024 f32, fully written)
// [20480,20484)        e_geom scalar
// [32768, +4MB)        xb  (4096x512 bf16)
// [+4MB, +55.4MB)      mub (50000x512 bf16)
// [+55.4MB, +65.9MB)   cand keys (4096 x 640 u32 = {bf16val:16, idx:16})

__global__ __launch_bounds__(256) void k_cast(const float* __restrict__ src,
                                              u16* __restrict__ dst, int n8) {
    int i = blockIdx.x * 256 + threadIdx.x;
    if (i >= n8) return;
    const float4* s4 = (const float4*)src;
    float4 a = s4[(size_t)i * 2], b = s4[(size_t)i * 2 + 1];
    u16x8 o;
    o[0] = f2bf(a.x); o[1] = f2bf(a.y); o[2] = f2bf(a.z); o[3] = f2bf(a.w);
    o[4] = f2bf(b.x); o[5] = f2bf(b.y); o[6] = f2bf(b.z); o[7] = f2bf(b.w);
    *(u16x8*)(dst + (size_t)i * 8) = o;
}

// ============ bf16 MFMA GEMM x @ mu^T with threshold push ============
// 128x128 tile, BK=64, 4 waves (2x2), double-buffered LDS (64KB),
// 2-phase pipeline: STAGE(next) issued before COMPUTE(cur), single barrier.
// Grid: x = row-panels (32, fastest) so concurrent blocks share mu col-tiles.
__global__ __launch_bounds__(256) void k_gemm_topk(
    const u16* __restrict__ xb, const u16* __restrict__ mub,
    u32* __restrict__ cnt, u32* __restrict__ cand)
{
    __shared__ uint4 smem[4096];          // 64 KB: 2 x (16KB A + 16KB B)

    const int t = threadIdx.x;
    const int lane = t & 63;
    const int wid = t >> 6;
    const int wr = wid >> 1, wc = wid & 1;
    const int fr = lane & 15, fq = lane >> 4;
    const int r0 = blockIdx.x * 128;      // row panel (fastest)
    const int c0 = blockIdx.y * 128;      // mu col tile

    f32x4 acc[4][4];
    const f32x4 zero = {0.f, 0.f, 0.f, 0.f};
#pragma unroll
    for (int m = 0; m < 4; ++m)
#pragma unroll
        for (int n = 0; n < 4; ++n) acc[m][n] = zero;

    const int swz = (fr & 7) << 4;

    auto STAGE = [&](int cur, int kt) {
        char* Ab = (char*)smem + cur * 32768;
        char* Bb = Ab + 16384;
#pragma unroll
        for (int i = 0; i < 4; ++i) {
            const int L  = i * 4096 + t * 16;
            const int rw = L >> 7;
            const int cb = (L & 127) ^ ((rw & 7) << 4);
            const char* srcA = (const char*)xb + ((size_t)(r0 + rw) * DD + kt) * 2 + cb;
            __builtin_amdgcn_global_load_lds((const AS1 u32*)srcA, (AS3 u32*)(Ab + L), 16, 0, 0);
            int gr = c0 + rw; if (gr > MM - 1) gr = MM - 1;   // clamp, filtered at push
            const char* srcB = (const char*)mub + ((size_t)gr * DD + kt) * 2 + cb;
            __builtin_amdgcn_global_load_lds((const AS1 u32*)srcB, (AS3 u32*)(Bb + L), 16, 0, 0);
        }
    };

    auto COMPUTE = [&](int cur) {
        const char* Ab = (const char*)smem + cur * 32768;
        const char* Bb = Ab + 16384;
#pragma unroll
        for (int kk = 0; kk < 64; kk += 32) {
            bf16x8 af[4], bfr[4];
#pragma unroll
            for (int m = 0; m < 4; ++m) {
                const int ra = wr * 64 + m * 16 + fr;
                af[m] = *(const bf16x8*)(Ab + ((ra << 7) | ((kk * 2 + fq * 16) ^ swz)));
            }
#pragma unroll
            for (int n = 0; n < 4; ++n) {
                const int rb = wc * 64 + n * 16 + fr;
                bfr[n] = *(const bf16x8*)(Bb + ((rb << 7) | ((kk * 2 + fq * 16) ^ swz)));
            }
#pragma unroll
            for (int m = 0; m < 4; ++m)
#pragma unroll
                for (int n = 0; n < 4; ++n)
                    acc[m][n] = __builtin_amdgcn_mfma_f32_16x16x32_bf16(af[m], bfr[n], acc[m][n], 0, 0, 0);
        }
    };

    STAGE(0, 0);
    __syncthreads();
#pragma unroll
    for (int ts = 0; ts < 7; ++ts) {
        const int cur = ts & 1;
        STAGE(cur ^ 1, (ts + 1) * 64);
        COMPUTE(cur);
        __syncthreads();
    }
    COMPUTE(1);

    // C/D layout (m89): col = lane&15, row = (lane>>4)*4 + reg
#pragma unroll
    for (int m = 0; m < 4; ++m) {
        const int rowb = r0 + wr * 64 + m * 16 + fq * 4;
#pragma unroll
        for (int n = 0; n < 4; ++n) {
            const int col = c0 + wc * 64 + n * 16 + fr;
#pragma unroll
            for (int r = 0; r < 4; ++r) {
                const float v = acc[m][n][r];
                if (v >= T0 && col < MM) {
                    u32 pos = atomicAdd(&cnt[rowb + r], 1u);
                    if (pos < CAP)
                        cand[(size_t)(rowb + r) * CAP + pos] =
                            (((u32)f2bf(v)) << 16) | (u32)col;
                }
            }
        }
    }
}

// ============ x @ x^T geometric energy (bf16 MFMA, triangular, dbuf) ========
__global__ __launch_bounds__(256) void k_geom(
    const u16* __restrict__ xb, float* __restrict__ partial)
{
    const int bx = blockIdx.x, by = blockIdx.y;
    const int t = threadIdx.x;
    if (bx < by) { if (t == 0) partial[by * 32 + bx] = 0.f; return; }

    __shared__ uint4 smem[4096];
    __shared__ float red[4];

    const int lane = t & 63;
    const int wid = t >> 6;
    const int wr = wid >> 1, wc = wid & 1;
    const int fr = lane & 15, fq = lane >> 4;
    const int r0 = by * 128;
    const int c0 = bx * 128;

    f32x4 acc[4][4];
    const f32x4 zero = {0.f, 0.f, 0.f, 0.f};
#pragma unroll
    for (int m = 0; m < 4; ++m)
#pragma unroll
        for (int n = 0; n < 4; ++n) acc[m][n] = zero;

    const int swz = (fr & 7) << 4;

    auto STAGE = [&](int cur, int kt) {
        char* Ab = (char*)smem + cur * 32768;
        char* Bb = Ab + 16384;
#pragma unroll
        for (int i = 0; i < 4; ++i) {
            const int L  = i * 4096 + t * 16;
            const int rw = L >> 7;
            const int cb = (L & 127) ^ ((rw & 7) << 4);
            const char* srcA = (const char*)xb + ((size_t)(r0 + rw) * DD + kt) * 2 + cb;
            __builtin_amdgcn_global_load_lds((const AS1 u32*)srcA, (AS3 u32*)(Ab + L), 16, 0, 0);
            const char* srcB = (const char*)xb + ((size_t)(c0 + rw) * DD + kt) * 2 + cb;
            __builtin_amdgcn_global_load_lds((const AS1 u32*)srcB, (AS3 u32*)(Bb + L), 16, 0, 0);
        }
    };

    auto COMPUTE = [&](int cur) {
        const char* Ab = (const char*)smem + cur * 32768;
        const char* Bb = Ab + 16384;
#pragma unroll
        for (int kk = 0; kk < 64; kk += 32) {
            bf16x8 af[4], bfr[4];
#pragma unroll
            for (int m = 0; m < 4; ++m) {
                const int ra = wr * 64 + m * 16 + fr;
                af[m] = *(const bf16x8*)(Ab + ((ra << 7) | ((kk * 2 + fq * 16) ^ swz)));
            }
#pragma unroll
            for (int n = 0; n < 4; ++n) {
                const int rb = wc * 64 + n * 16 + fr;
                bfr[n] = *(const bf16x8*)(Bb + ((rb << 7) | ((kk * 2 + fq * 16) ^ swz)));
            }
#pragma unroll
            for (int m = 0; m < 4; ++m)
#pragma unroll
                for (int n = 0; n < 4; ++n)
                    acc[m][n] = __builtin_amdgcn_mfma_f32_16x16x32_bf16(af[m], bfr[n], acc[m][n], 0, 0, 0);
        }
    };

    STAGE(0, 0);
    __syncthreads();
#pragma unroll
    for (int ts = 0; ts < 7; ++ts) {
        const int cur = ts & 1;
        STAGE(cur ^ 1, (ts + 1) * 64);
        COMPUTE(cur);
        __syncthreads();
    }
    COMPUTE(1);

    float local = 0.f;
#pragma unroll
    for (int m = 0; m < 4; ++m) {
        const int rowb = r0 + wr * 64 + m * 16 + fq * 4;
#pragma unroll
        for (int n = 0; n < 4; ++n) {
            const int col = c0 + wc * 64 + n * 16 + fr;
#pragma unroll
            for (int r = 0; r < 4; ++r) {
                if (rowb + r != col) {
                    float s = fminf(acc[m][n][r], 0.9999f);
                    local += -logf(1.0f - s + 1e-4f);
                }
            }
        }
    }
    if (bx > by) local *= 2.f;   // symmetric half counted twice

#pragma unroll
    for (int off = 32; off >= 1; off >>= 1) local += __shfl_xor(local, off, 64);
    if (lane == 0) red[wid] = local;
    __syncthreads();
    if (t == 0) partial[by * 32 + bx] = red[0] + red[1] + red[2] + red[3];
}

__global__ void k_reduce_geom(const float* __restrict__ partial, float* __restrict__ egeom)
{
    __shared__ float red[16];
    const int t = threadIdx.x;
    float v = partial[t];
#pragma unroll
    for (int off = 32; off >= 1; off >>= 1) v += __shfl_xor(v, off, 64);
    const int wave = t >> 6, lane = t & 63;
    if (lane == 0) red[wave] = v;
    __syncthreads();
    if (t == 0) {
        float s = 0.f;
        for (int i = 0; i < 16; ++i) s += red[i];
        egeom[0] = s / ((float)NR * (float)(NR - 1));
    }
}

// ============ top-64 by key -> exact fp32 recompute -> top-32 -> epilogue ====
__global__ __launch_bounds__(256) void k_finalize(
    const u32* __restrict__ cand, const u32* __restrict__ cnt,
    const float* __restrict__ x, const float* __restrict__ mu,
    const float* __restrict__ alpha, const float* __restrict__ kappa,
    const float* __restrict__ Ww, const float* __restrict__ Wb,
    const float* __restrict__ egeom, float* __restrict__ out)
{
    __shared__ u32   keys[4][CAP];
    __shared__ int   selid[4][TK];
    __shared__ float selex[4][TK];

    const int t = threadIdx.x, wave = t >> 6, lane = t & 63;
    const int row = blockIdx.x * 4 + wave;
    const int cn = (int)cnt[row];
    const int c = cn < CAP ? cn : CAP;

    for (int s = lane; s < c; s += 64)
        keys[wave][s] = cand[(size_t)row * CAP + s];
    __syncthreads();

    // iterative argmax: top-TK keys (value-major; distinct idx => no ties)
    for (int k = 0; k < TK; ++k) {
        u32 best = 0u; int bpos = -1;
        for (int s = lane; s < c; s += 64) {
            u32 v = keys[wave][s];
            if (v > best) { best = v; bpos = s; }
        }
#pragma unroll
        for (int off = 32; off >= 1; off >>= 1) {
            u32 v2 = __shfl_xor(best, off, 64);
            int p2 = __shfl_xor(bpos, off, 64);
            if (v2 > best) { best = v2; bpos = p2; }
        }
        if (lane == 0) {
            selid[wave][k] = (bpos >= 0) ? (int)(best & 0xFFFFu) : -1;
            if (bpos >= 0) keys[wave][bpos] = 0u;
        }
        __syncthreads();
    }

    // exact fp32 dots for the TK selected candidates
    float xr[8];
    {
        const float4* xp = (const float4*)(x + (size_t)row * DD);
        float4 a = xp[lane * 2], b = xp[lane * 2 + 1];
        xr[0] = a.x; xr[1] = a.y; xr[2] = a.z; xr[3] = a.w;
        xr[4] = b.x; xr[5] = b.y; xr[6] = b.z; xr[7] = b.w;
    }
    for (int s = 0; s < TK; ++s) {
        const int id = selid[wave][s];          // wave-uniform
        if (id >= 0) {
            const float4* mp = (const float4*)(mu + (size_t)id * DD);
            float4 a = mp[lane * 2], b = mp[lane * 2 + 1];
            float d = xr[0] * a.x + xr[1] * a.y + xr[2] * a.z + xr[3] * a.w
                    + xr[4] * b.x + xr[5] * b.y + xr[6] * b.z + xr[7] * b.w;
#pragma unroll
            for (int off = 32; off >= 1; off >>= 1) d += __shfl_xor(d, off, 64);
            if (lane == 0) selex[wave][s] = d;
        } else if (lane == 0) {
            selex[wave][s] = -INFINITY;
        }
    }
    __syncthreads();

    float v = selex[wave][lane];
    const int id = selid[wave][lane];
    bool alive = (id >= 0);

    // drop the 32 smallest exact values -> exact top-32 remains
    for (int rdrop = 0; rdrop < 32; ++rdrop) {
        float mn = alive ? v : INFINITY;
        int  mp2 = alive ? lane : 64;
#pragma unroll
        for (int off = 32; off >= 1; off >>= 1) {
            float m2 = __shfl_xor(mn, off, 64);
            int   p2 = __shfl_xor(mp2, off, 64);
            if (m2 < mn || (m2 == mn && p2 < mp2)) { mn = m2; mp2 = p2; }
        }
        if (lane == mp2) alive = false;
    }

    const float dv = alive ? v : -INFINITY;

    // top-1 / top-2 exact values (u, v of the reference)
    float m1 = dv; int p1 = alive ? lane : 64;
#pragma unroll
    for (int off = 32; off >= 1; off >>= 1) {
        float m2 = __shfl_xor(m1, off, 64);
        int   p2 = __shfl_xor(p1, off, 64);
        if (m2 > m1 || (m2 == m1 && p2 < p1)) { m1 = m2; p1 = p2; }
    }
    const float uu = m1;
    float s1 = (lane == p1) ? -INFINITY : dv;
#pragma unroll
    for (int off = 32; off >= 1; off >>= 1) s1 = fmaxf(s1, __shfl_xor(s1, off, 64));
    const float vv = s1;

    const int gid = alive ? id : 0;
    const float av = alpha[gid];
    const float kv = kappa[gid];
    float imp = alive ? fmaxf(kv, 1e-4f) : 0.f;
    float simp = imp;
#pragma unroll
    for (int off = 32; off >= 1; off >>= 1) simp += __shfl_xor(simp, off, 64);
    float w = fmaxf(imp / simp, 1e-8f);
    float tk = alive ? (av * (dv - 1.0f) * 10.0f + logf(w)) : -INFINITY;
    float mx = tk;
#pragma unroll
    for (int off = 32; off >= 1; off >>= 1) mx = fmaxf(mx, __shfl_xor(mx, off, 64));
    float se = alive ? expf(tk - mx) : 0.f;
#pragma unroll
    for (int off = 32; off >= 1; off >>= 1) se += __shfl_xor(se, off, 64);

    if (lane == 0) {
        float esplat = -(mx + logf(se));
        float z = Ww[0] * uu + Ww[1] * vv + Ww[2] * uu * vv + Wb[0];
        float ecomp = 1.f / (1.f + expf(-z));
        out[row] = esplat + 0.1f * egeom[0] + 0.1f * ecomp;
    }
}

extern "C" void kernel_launch(void* const* d_in, const int* in_sizes, int n_in,
                              void* d_out, int out_size, void* d_ws, size_t ws_size,
                              hipStream_t stream)
{
    const float* x     = (const float*)d_in[0];
    const float* mu    = (const float*)d_in[1];
    const float* alpha = (const float*)d_in[2];
    const float* kappa = (const float*)d_in[3];
    const float* Ww    = (const float*)d_in[4];
    const float* Wb    = (const float*)d_in[5];
    float* out = (float*)d_out;

    char* ws = (char*)d_ws;
    u32*   cnt     = (u32*)ws;
    float* partial = (float*)(ws + 16384);
    float* egeom   = (float*)(ws + 20480);
    u16*   xb      = (u16*)(ws + 32768);
    u16*   mub     = (u16*)(ws + 32768 + 4194304);
    u32*   cand    = (u32*)(ws + 32768 + 4194304 + 51200000);

    hipMemsetAsync(cnt, 0, NR * sizeof(u32), stream);

    k_cast<<<(NR * DD / 8) / 256, 256, 0, stream>>>(x, xb, NR * DD / 8);
    k_cast<<<(MM * DD / 8) / 256, 256, 0, stream>>>(mu, mub, MM * DD / 8);

    dim3 g1(NR / 128, (MM + 127) / 128);   // 32 x 391, row-panel fastest
    k_gemm_topk<<<g1, 256, 0, stream>>>(xb, mub, cnt, cand);

    dim3 g2(32, 32);
    k_geom<<<g2, 256, 0, stream>>>(xb, partial);

    k_reduce_geom<<<1, 1024, 0, stream>>>(partial, egeom);

    k_finalize<<<NR / 4, 256, 0, stream>>>(cand, cnt, x, mu, alpha, kappa, Ww, Wb, egeom, out);
}